// Round 1
// baseline (14952.470 us; speedup 1.0000x reference)
//
#include <hip/hip_runtime.h>
#include <hip/hip_bf16.h>
#include <math.h>

#define T_STEPS 256
#define BATCH   128
#define IN_DIM  1024
#define LAT     2048

typedef __bf16 bf16x8 __attribute__((ext_vector_type(8)));
typedef __bf16 bf16x4 __attribute__((ext_vector_type(4)));
typedef float  f32x4  __attribute__((ext_vector_type(4)));

// LDS tiles are [ROWS][32] bf16, row stride 64 B. XOR-swizzle bits 4..6 by row
// to break the 8-way bank conflict on ds_read_b128 fragment loads (2-way = free).
__device__ __forceinline__ int swz(int row, int kbyte) {
    return (row * 64 + kbyte) ^ ((row & 7) << 4);
}

// Stage a ROWS x 32 fp32 tile from global, splitting each value into
// hi = bf16(x), lo = bf16(x - hi). 256 threads, float4 per thread per round.
template<int ROWS>
__device__ __forceinline__ void stage_split(const float* __restrict__ src, int ld,
                                            char* hi, char* lo, int tid) {
#pragma unroll
    for (int rnd = 0; rnd < ROWS / 32; ++rnd) {
        int r  = rnd * 32 + (tid >> 3);
        int kc = (tid & 7) * 4;                       // element offset in K
        f32x4 v = *(const f32x4*)(src + (size_t)r * ld + kc);
        bf16x4 vh, vl;
#pragma unroll
        for (int e = 0; e < 4; ++e) {
            float x = v[e];
            __bf16 h = (__bf16)x;
            vh[e] = h;
            vl[e] = (__bf16)(x - (float)h);
        }
        int off = swz(r, kc * 2);
        *(bf16x4*)(hi + off) = vh;
        *(bf16x4*)(lo + off) = vl;
    }
}

__device__ __forceinline__ bf16x8 ld_frag(const char* p, int row, int kb) {
    return *(const bf16x8*)(p + swz(row, kb));
}

// xi = x @ W_i^T + b_i  -> out (fp32). Rows < BATCH (t=0) additionally get tanh.
// Tile 128x128, BK=32, 4 waves each 64x64 (4x4 fragments of 16x16x32).
__global__ __launch_bounds__(256, 2)
void k_xproj(const float* __restrict__ x, const float* __restrict__ Wi,
             const float* __restrict__ bi, float* __restrict__ out)
{
    __shared__ __align__(16) char lds[32 * 1024];
    char* Ahi = lds;
    char* Alo = lds + 8192;
    char* Bhi = lds + 16384;
    char* Blo = lds + 24576;

    int tid  = threadIdx.x;
    int lane = tid & 63;
    int w    = tid >> 6;
    int wm   = (w >> 1) * 64;
    int wn   = (w & 1) * 64;
    int bm   = blockIdx.y * 128;
    int bn   = blockIdx.x * 128;

    f32x4 acc[4][4] = {};

    for (int k0 = 0; k0 < IN_DIM; k0 += 32) {
        __syncthreads();
        stage_split<128>(x  + (size_t)bm * IN_DIM + k0, IN_DIM, Ahi, Alo, tid);
        stage_split<128>(Wi + (size_t)bn * IN_DIM + k0, IN_DIM, Bhi, Blo, tid);
        __syncthreads();

        int kb = (lane >> 4) * 16;   // byte offset of this lane's 8 bf16 in K
        bf16x8 ah[4], al[4], bh[4], bl[4];
#pragma unroll
        for (int i = 0; i < 4; ++i) {
            int ra = wm + i * 16 + (lane & 15);
            ah[i] = ld_frag(Ahi, ra, kb);
            al[i] = ld_frag(Alo, ra, kb);
            int rb = wn + i * 16 + (lane & 15);
            bh[i] = ld_frag(Bhi, rb, kb);
            bl[i] = ld_frag(Blo, rb, kb);
        }
#pragma unroll
        for (int i = 0; i < 4; ++i)
#pragma unroll
            for (int j = 0; j < 4; ++j) {
                acc[i][j] = __builtin_amdgcn_mfma_f32_16x16x32_bf16(ah[i], bh[j], acc[i][j], 0, 0, 0);
                acc[i][j] = __builtin_amdgcn_mfma_f32_16x16x32_bf16(ah[i], bl[j], acc[i][j], 0, 0, 0);
                acc[i][j] = __builtin_amdgcn_mfma_f32_16x16x32_bf16(al[i], bh[j], acc[i][j], 0, 0, 0);
            }
    }

#pragma unroll
    for (int j = 0; j < 4; ++j) {
        int n = bn + wn + j * 16 + (lane & 15);
        float bias = bi[n];
#pragma unroll
        for (int i = 0; i < 4; ++i) {
            int m0 = bm + wm + i * 16 + ((lane >> 4) * 4);
#pragma unroll
            for (int r = 0; r < 4; ++r) {
                float v = acc[i][j][r] + bias;
                if (m0 + r < BATCH) v = tanhf(v);   // t == 0: h0 = tanh(xi)
                out[(size_t)(m0 + r) * LAT + n] = v;
            }
        }
    }
}

// One recurrence step: io[m][n] = tanh(io[m][n] + hprev @ Wh^T + bh).
// Tile 32x128, 4 waves each 32x32 (2x2 fragments), full K=2048.
__global__ __launch_bounds__(256, 2)
void k_step(const float* __restrict__ hprev, const float* __restrict__ Wh,
            const float* __restrict__ bh_, float* __restrict__ io)
{
    __shared__ __align__(16) char lds[20 * 1024];
    char* Ahi = lds;
    char* Alo = lds + 2048;
    char* Bhi = lds + 4096;
    char* Blo = lds + 12288;

    int tid  = threadIdx.x;
    int lane = tid & 63;
    int w    = tid >> 6;
    int bm   = blockIdx.y * 32;
    int bn   = blockIdx.x * 128;
    int wn   = w * 32;

    f32x4 acc[2][2] = {};

    for (int k0 = 0; k0 < LAT; k0 += 32) {
        __syncthreads();
        stage_split<32>(hprev + (size_t)bm * LAT + k0, LAT, Ahi, Alo, tid);
        stage_split<128>(Wh   + (size_t)bn * LAT + k0, LAT, Bhi, Blo, tid);
        __syncthreads();

        int kb = (lane >> 4) * 16;
        bf16x8 ah[2], al[2], bh[2], bl[2];
#pragma unroll
        for (int i = 0; i < 2; ++i) {
            int ra = i * 16 + (lane & 15);
            ah[i] = ld_frag(Ahi, ra, kb);
            al[i] = ld_frag(Alo, ra, kb);
            int rb = wn + i * 16 + (lane & 15);
            bh[i] = ld_frag(Bhi, rb, kb);
            bl[i] = ld_frag(Blo, rb, kb);
        }
#pragma unroll
        for (int i = 0; i < 2; ++i)
#pragma unroll
            for (int j = 0; j < 2; ++j) {
                acc[i][j] = __builtin_amdgcn_mfma_f32_16x16x32_bf16(ah[i], bh[j], acc[i][j], 0, 0, 0);
                acc[i][j] = __builtin_amdgcn_mfma_f32_16x16x32_bf16(ah[i], bl[j], acc[i][j], 0, 0, 0);
                acc[i][j] = __builtin_amdgcn_mfma_f32_16x16x32_bf16(al[i], bh[j], acc[i][j], 0, 0, 0);
            }
    }

#pragma unroll
    for (int j = 0; j < 2; ++j) {
        int n = bn + wn + j * 16 + (lane & 15);
        float bias = bh_[n];
#pragma unroll
        for (int i = 0; i < 2; ++i) {
            int m0 = bm + i * 16 + ((lane >> 4) * 4);
#pragma unroll
            for (int r = 0; r < 4; ++r) {
                size_t idx = (size_t)(m0 + r) * LAT + n;
                io[idx] = tanhf(acc[i][j][r] + bias + io[idx]);
            }
        }
    }
}

extern "C" void kernel_launch(void* const* d_in, const int* in_sizes, int n_in,
                              void* d_out, int out_size, void* d_ws, size_t ws_size,
                              hipStream_t stream) {
    const float* x  = (const float*)d_in[0];
    const float* Wi = (const float*)d_in[1];
    const float* bi = (const float*)d_in[2];
    const float* Wh = (const float*)d_in[3];
    const float* bh = (const float*)d_in[4];
    float* out = (float*)d_out;

    // Phase 1: xi (+bias) for all timesteps straight into d_out; tanh on t=0 rows.
    dim3 g1(LAT / 128, (T_STEPS * BATCH) / 128);   // (16, 256)
    k_xproj<<<g1, 256, 0, stream>>>(x, Wi, bi, out);

    // Phase 2: sequential recurrence, in-place on out[t].
    dim3 g2(LAT / 128, BATCH / 32);                // (16, 4) = 64 WGs
    for (int t = 1; t < T_STEPS; ++t) {
        k_step<<<g2, 256, 0, stream>>>(out + (size_t)(t - 1) * BATCH * LAT,
                                       Wh, bh,
                                       out + (size_t)t * BATCH * LAT);
    }
}

// Round 2
// 4821.839 us; speedup vs baseline: 3.1010x; 3.1010x over previous
//
#include <hip/hip_runtime.h>
#include <hip/hip_bf16.h>
#include <math.h>

#define T_STEPS 256
#define BATCH   128
#define IN_DIM  1024
#define LAT     2048

typedef __bf16 bf16x8 __attribute__((ext_vector_type(8)));
typedef __bf16 bf16x4 __attribute__((ext_vector_type(4)));
typedef float  f32x4  __attribute__((ext_vector_type(4)));

// ---------------------------------------------------------------------------
// Shared helpers (k_xproj staging path)
// ---------------------------------------------------------------------------
// LDS tiles are [ROWS][32] bf16, row stride 64 B. XOR-swizzle (consistent on
// write and read sides -> bijective) spreads fragment reads across 8 bank
// groups: 2-way conflict = free (m136).
__device__ __forceinline__ int swz(int row, int kbyte) {
    return (row * 64 + kbyte) ^ ((row & 7) << 4);
}

template<int ROWS>
__device__ __forceinline__ void stage_split(const float* __restrict__ src, int ld,
                                            char* hi, char* lo, int tid) {
#pragma unroll
    for (int rnd = 0; rnd < ROWS / 32; ++rnd) {
        int r  = rnd * 32 + (tid >> 3);
        int kc = (tid & 7) * 4;
        f32x4 v = *(const f32x4*)(src + (size_t)r * ld + kc);
        bf16x4 vh, vl;
#pragma unroll
        for (int e = 0; e < 4; ++e) {
            float x = v[e];
            __bf16 h = (__bf16)x;
            vh[e] = h;
            vl[e] = (__bf16)(x - (float)h);
        }
        int off = swz(r, kc * 2);
        *(bf16x4*)(hi + off) = vh;
        *(bf16x4*)(lo + off) = vl;
    }
}

__device__ __forceinline__ bf16x8 ld_frag(const char* p, int row, int kb) {
    return *(const bf16x8*)(p + swz(row, kb));
}

// Split two f32x4 (8 consecutive K elems) into hi/lo bf16x8 fragments.
__device__ __forceinline__ void split8(f32x4 v0, f32x4 v1, bf16x8& hi, bf16x8& lo) {
#pragma unroll
    for (int e = 0; e < 4; ++e) {
        __bf16 h0 = (__bf16)v0[e];
        hi[e]     = h0;
        lo[e]     = (__bf16)(v0[e] - (float)h0);
        __bf16 h1 = (__bf16)v1[e];
        hi[e + 4] = h1;
        lo[e + 4] = (__bf16)(v1[e] - (float)h1);
    }
}

// ---------------------------------------------------------------------------
// Phase 1: xi = x @ W_i^T + b_i  -> out (fp32); t==0 rows get tanh.
// 128x128 tile, BK=32, 4 waves each 64x64. (Unchanged from round 1.)
// ---------------------------------------------------------------------------
__global__ __launch_bounds__(256, 2)
void k_xproj(const float* __restrict__ x, const float* __restrict__ Wi,
             const float* __restrict__ bi, float* __restrict__ out)
{
    __shared__ __align__(16) char lds[32 * 1024];
    char* Ahi = lds;
    char* Alo = lds + 8192;
    char* Bhi = lds + 16384;
    char* Blo = lds + 24576;

    int tid  = threadIdx.x;
    int lane = tid & 63;
    int w    = tid >> 6;
    int wm   = (w >> 1) * 64;
    int wn   = (w & 1) * 64;
    int bm   = blockIdx.y * 128;
    int bn   = blockIdx.x * 128;

    f32x4 acc[4][4] = {};

    for (int k0 = 0; k0 < IN_DIM; k0 += 32) {
        __syncthreads();
        stage_split<128>(x  + (size_t)bm * IN_DIM + k0, IN_DIM, Ahi, Alo, tid);
        stage_split<128>(Wi + (size_t)bn * IN_DIM + k0, IN_DIM, Bhi, Blo, tid);
        __syncthreads();

        int kb = (lane >> 4) * 16;
        bf16x8 ah[4], al[4], bh[4], bl[4];
#pragma unroll
        for (int i = 0; i < 4; ++i) {
            int ra = wm + i * 16 + (lane & 15);
            ah[i] = ld_frag(Ahi, ra, kb);
            al[i] = ld_frag(Alo, ra, kb);
            int rb = wn + i * 16 + (lane & 15);
            bh[i] = ld_frag(Bhi, rb, kb);
            bl[i] = ld_frag(Blo, rb, kb);
        }
#pragma unroll
        for (int i = 0; i < 4; ++i)
#pragma unroll
            for (int j = 0; j < 4; ++j) {
                acc[i][j] = __builtin_amdgcn_mfma_f32_16x16x32_bf16(ah[i], bh[j], acc[i][j], 0, 0, 0);
                acc[i][j] = __builtin_amdgcn_mfma_f32_16x16x32_bf16(ah[i], bl[j], acc[i][j], 0, 0, 0);
                acc[i][j] = __builtin_amdgcn_mfma_f32_16x16x32_bf16(al[i], bh[j], acc[i][j], 0, 0, 0);
            }
    }

#pragma unroll
    for (int j = 0; j < 4; ++j) {
        int n = bn + wn + j * 16 + (lane & 15);
        float bias = bi[n];
#pragma unroll
        for (int i = 0; i < 4; ++i) {
            int m0 = bm + wm + i * 16 + ((lane >> 4) * 4);
#pragma unroll
            for (int r = 0; r < 4; ++r) {
                float v = acc[i][j][r] + bias;
                if (m0 + r < BATCH) v = tanhf(v);   // t == 0: h0 = tanh(xi)
                out[(size_t)(m0 + r) * LAT + n] = v;
            }
        }
    }
}

// ---------------------------------------------------------------------------
// Phase 2 (v2): one recurrence step, LDS-free main loop.
//   io[m][n] = tanh(io[m][n] + hprev @ Wh^T + bh)
// Grid (64,4) = 256 WGs; WG tile 32x32; each of the 4 waves owns a K-quarter
// (512) and streams MFMA fragments DIRECTLY from global (16 rows x 128 B =
// whole cache lines, zero waste), converting fp32 -> hi/lo bf16 in-register.
// Cross-wave K-reduction via a 16 KB LDS partial buffer + one barrier.
// ---------------------------------------------------------------------------
__global__ __launch_bounds__(256, 2)
void k_step(const float* __restrict__ hprev, const float* __restrict__ Wh,
            const float* __restrict__ bias, float* __restrict__ io)
{
    __shared__ __align__(16) float part[4][32][32];   // [wave][row][col]

    const int tid  = threadIdx.x;
    const int lane = tid & 63;
    const int w    = tid >> 6;           // wave id == K-split index
    const int bn   = blockIdx.x * 32;    // output cols (rows of Wh)
    const int bm   = blockIdx.y * 32;    // batch rows

    const int fr = lane & 15;            // fragment row within 16
    const int kq = (lane >> 4) * 8;      // fragment K sub-offset (elements)

    const float* A0 = hprev + (size_t)(bm + fr)      * LAT;
    const float* A1 = hprev + (size_t)(bm + 16 + fr) * LAT;
    const float* B0 = Wh    + (size_t)(bn + fr)      * LAT;
    const float* B1 = Wh    + (size_t)(bn + 16 + fr) * LAT;

    f32x4 acc[2][2] = {};

    const int kbase = w * 512 + kq;
#pragma unroll
    for (int i = 0; i < 16; ++i) {
        const int k = kbase + i * 32;

        f32x4 a00 = *(const f32x4*)(A0 + k);
        f32x4 a01 = *(const f32x4*)(A0 + k + 4);
        f32x4 a10 = *(const f32x4*)(A1 + k);
        f32x4 a11 = *(const f32x4*)(A1 + k + 4);
        f32x4 b00 = *(const f32x4*)(B0 + k);
        f32x4 b01 = *(const f32x4*)(B0 + k + 4);
        f32x4 b10 = *(const f32x4*)(B1 + k);
        f32x4 b11 = *(const f32x4*)(B1 + k + 4);

        bf16x8 ah0, al0, ah1, al1, bh0, bl0, bh1, bl1;
        split8(a00, a01, ah0, al0);
        split8(a10, a11, ah1, al1);
        split8(b00, b01, bh0, bl0);
        split8(b10, b11, bh1, bl1);

        // 12 MFMAs, interleaved across 4 independent accumulators for ILP.
        acc[0][0] = __builtin_amdgcn_mfma_f32_16x16x32_bf16(ah0, bh0, acc[0][0], 0, 0, 0);
        acc[0][1] = __builtin_amdgcn_mfma_f32_16x16x32_bf16(ah0, bh1, acc[0][1], 0, 0, 0);
        acc[1][0] = __builtin_amdgcn_mfma_f32_16x16x32_bf16(ah1, bh0, acc[1][0], 0, 0, 0);
        acc[1][1] = __builtin_amdgcn_mfma_f32_16x16x32_bf16(ah1, bh1, acc[1][1], 0, 0, 0);

        acc[0][0] = __builtin_amdgcn_mfma_f32_16x16x32_bf16(al0, bh0, acc[0][0], 0, 0, 0);
        acc[0][1] = __builtin_amdgcn_mfma_f32_16x16x32_bf16(al0, bh1, acc[0][1], 0, 0, 0);
        acc[1][0] = __builtin_amdgcn_mfma_f32_16x16x32_bf16(al1, bh0, acc[1][0], 0, 0, 0);
        acc[1][1] = __builtin_amdgcn_mfma_f32_16x16x32_bf16(al1, bh1, acc[1][1], 0, 0, 0);

        acc[0][0] = __builtin_amdgcn_mfma_f32_16x16x32_bf16(ah0, bl0, acc[0][0], 0, 0, 0);
        acc[0][1] = __builtin_amdgcn_mfma_f32_16x16x32_bf16(ah0, bl1, acc[0][1], 0, 0, 0);
        acc[1][0] = __builtin_amdgcn_mfma_f32_16x16x32_bf16(ah1, bl0, acc[1][0], 0, 0, 0);
        acc[1][1] = __builtin_amdgcn_mfma_f32_16x16x32_bf16(ah1, bl1, acc[1][1], 0, 0, 0);
    }

    // Dump this wave's 32x32 partial into LDS.
    // C-frag layout (m89-verified): col = lane&15, row = (lane>>4)*4 + reg.
#pragma unroll
    for (int mi = 0; mi < 2; ++mi)
#pragma unroll
        for (int nj = 0; nj < 2; ++nj)
#pragma unroll
            for (int r = 0; r < 4; ++r)
                part[w][mi * 16 + (lane >> 4) * 4 + r][nj * 16 + fr] = acc[mi][nj][r];

    __syncthreads();

    // Combine: 256 threads, each owns 4 consecutive output cols of one row.
    const int row = tid >> 3;
    const int c   = (tid & 7) * 4;
    f32x4 s0 = *(const f32x4*)&part[0][row][c];
    f32x4 s1 = *(const f32x4*)&part[1][row][c];
    f32x4 s2 = *(const f32x4*)&part[2][row][c];
    f32x4 s3 = *(const f32x4*)&part[3][row][c];

    float* outp = io + (size_t)(bm + row) * LAT + bn + c;
    f32x4 xv = *(const f32x4*)outp;
    f32x4 bv = *(const f32x4*)(bias + bn + c);
    f32x4 o;
#pragma unroll
    for (int e = 0; e < 4; ++e)
        o[e] = tanhf(s0[e] + s1[e] + s2[e] + s3[e] + xv[e] + bv[e]);
    *(f32x4*)outp = o;
}

extern "C" void kernel_launch(void* const* d_in, const int* in_sizes, int n_in,
                              void* d_out, int out_size, void* d_ws, size_t ws_size,
                              hipStream_t stream) {
    const float* x  = (const float*)d_in[0];
    const float* Wi = (const float*)d_in[1];
    const float* bi = (const float*)d_in[2];
    const float* Wh = (const float*)d_in[3];
    const float* bh = (const float*)d_in[4];
    float* out = (float*)d_out;

    // Phase 1: xi (+bias) for all timesteps straight into d_out; tanh on t=0 rows.
    dim3 g1(LAT / 128, (T_STEPS * BATCH) / 128);   // (16, 256)
    k_xproj<<<g1, 256, 0, stream>>>(x, Wi, bi, out);

    // Phase 2: sequential recurrence, in-place on out[t].
    dim3 g2(LAT / 32, BATCH / 32);                 // (64, 4) = 256 WGs
    for (int t = 1; t < T_STEPS; ++t) {
        k_step<<<g2, 256, 0, stream>>>(out + (size_t)(t - 1) * BATCH * LAT,
                                       Wh, bh,
                                       out + (size_t)t * BATCH * LAT);
    }
}

// Round 3
// 4815.980 us; speedup vs baseline: 3.1048x; 1.0012x over previous
//
#include <hip/hip_runtime.h>
#include <hip/hip_bf16.h>
#include <math.h>

#define T_STEPS 256
#define BATCH   128
#define IN_DIM  1024
#define LAT     2048

typedef __bf16 bf16x8 __attribute__((ext_vector_type(8)));
typedef __bf16 bf16x4 __attribute__((ext_vector_type(4)));
typedef float  f32x4  __attribute__((ext_vector_type(4)));

// ---------------------------------------------------------------------------
// LDS tile helpers: [ROWS][32] bf16, row stride 64 B, XOR-swizzled (same
// transform on write and read -> bijective; spreads b128 reads across banks).
// ---------------------------------------------------------------------------
__device__ __forceinline__ int swz(int row, int kbyte) {
    return (row * 64 + kbyte) ^ ((row & 7) << 4);
}

// Split-staging, two halves so the global load can be issued a K-tile early:
//   stage_load : global fp32 -> registers (f32x4 per 32-row round)
//   stage_write: registers -> hi/lo bf16 LDS tiles (split happens here)
template<int ROWS>
__device__ __forceinline__ void stage_load(const float* __restrict__ src, int ld,
                                           int tid, f32x4* regs) {
#pragma unroll
    for (int rnd = 0; rnd < ROWS / 32; ++rnd) {
        int r  = rnd * 32 + (tid >> 3);
        int kc = (tid & 7) * 4;
        regs[rnd] = *(const f32x4*)(src + (size_t)r * ld + kc);
    }
}

template<int ROWS>
__device__ __forceinline__ void stage_write(const f32x4* regs, char* hi, char* lo,
                                            int tid) {
#pragma unroll
    for (int rnd = 0; rnd < ROWS / 32; ++rnd) {
        int r  = rnd * 32 + (tid >> 3);
        int kc = (tid & 7) * 4;
        bf16x4 vh, vl;
        f32x4  v = regs[rnd];
#pragma unroll
        for (int e = 0; e < 4; ++e) {
            float x = v[e];
            __bf16 h = (__bf16)x;
            vh[e] = h;
            vl[e] = (__bf16)(x - (float)h);
        }
        int off = swz(r, kc * 2);
        *(bf16x4*)(hi + off) = vh;
        *(bf16x4*)(lo + off) = vl;
    }
}

__device__ __forceinline__ bf16x8 ld_frag(const char* p, int row, int kb) {
    return *(const bf16x8*)(p + swz(row, kb));
}

// Split two f32x4 (8 consecutive K elems) into hi/lo bf16x8 fragments.
__device__ __forceinline__ void split8(f32x4 v0, f32x4 v1, bf16x8& hi, bf16x8& lo) {
#pragma unroll
    for (int e = 0; e < 4; ++e) {
        __bf16 h0 = (__bf16)v0[e];
        hi[e]     = h0;
        lo[e]     = (__bf16)(v0[e] - (float)h0);
        __bf16 h1 = (__bf16)v1[e];
        hi[e + 4] = h1;
        lo[e + 4] = (__bf16)(v1[e] - (float)h1);
    }
}

// ---------------------------------------------------------------------------
// Phase 1: xi = x @ W_i^T + b_i  -> out (fp32); t==0 rows get tanh.
// 128x128 tile, BK=32, 4 waves each 64x64.
// v3: reg-prefetch 2-phase pipeline — next K-tile's global loads are issued
// before the MFMA block so HBM latency hides under 48 MFMAs.
// ---------------------------------------------------------------------------
__global__ __launch_bounds__(256, 2)
void k_xproj(const float* __restrict__ x, const float* __restrict__ Wi,
             const float* __restrict__ bi, float* __restrict__ out)
{
    __shared__ __align__(16) char lds[32 * 1024];
    char* Ahi = lds;
    char* Alo = lds + 8192;
    char* Bhi = lds + 16384;
    char* Blo = lds + 24576;

    int tid  = threadIdx.x;
    int lane = tid & 63;
    int w    = tid >> 6;
    int wm   = (w >> 1) * 64;
    int wn   = (w & 1) * 64;
    int bm   = blockIdx.y * 128;
    int bn   = blockIdx.x * 128;

    const float* Abase = x  + (size_t)bm * IN_DIM;
    const float* Bbase = Wi + (size_t)bn * IN_DIM;

    f32x4 acc[4][4] = {};
    f32x4 ra[4], rb[4];

    stage_load<128>(Abase, IN_DIM, tid, ra);
    stage_load<128>(Bbase, IN_DIM, tid, rb);

    for (int k0 = 0; k0 < IN_DIM; k0 += 32) {
        stage_write<128>(ra, Ahi, Alo, tid);
        stage_write<128>(rb, Bhi, Blo, tid);
        __syncthreads();

        if (k0 + 32 < IN_DIM) {                    // prefetch next K-tile
            stage_load<128>(Abase + k0 + 32, IN_DIM, tid, ra);
            stage_load<128>(Bbase + k0 + 32, IN_DIM, tid, rb);
        }

        int kb = (lane >> 4) * 16;
        bf16x8 ah[4], al[4], bh[4], bl[4];
#pragma unroll
        for (int i = 0; i < 4; ++i) {
            int rrow = i * 16 + (lane & 15);
            ah[i] = ld_frag(Ahi, wm + rrow, kb);
            al[i] = ld_frag(Alo, wm + rrow, kb);
            bh[i] = ld_frag(Bhi, wn + rrow, kb);
            bl[i] = ld_frag(Blo, wn + rrow, kb);
        }
#pragma unroll
        for (int i = 0; i < 4; ++i)
#pragma unroll
            for (int j = 0; j < 4; ++j) {
                acc[i][j] = __builtin_amdgcn_mfma_f32_16x16x32_bf16(ah[i], bh[j], acc[i][j], 0, 0, 0);
                acc[i][j] = __builtin_amdgcn_mfma_f32_16x16x32_bf16(ah[i], bl[j], acc[i][j], 0, 0, 0);
                acc[i][j] = __builtin_amdgcn_mfma_f32_16x16x32_bf16(al[i], bh[j], acc[i][j], 0, 0, 0);
            }
        __syncthreads();
    }

#pragma unroll
    for (int j = 0; j < 4; ++j) {
        int n = bn + wn + j * 16 + (lane & 15);
        float bias = bi[n];
#pragma unroll
        for (int i = 0; i < 4; ++i) {
            int m0 = bm + wm + i * 16 + ((lane >> 4) * 4);
#pragma unroll
            for (int r = 0; r < 4; ++r) {
                float v = acc[i][j][r] + bias;
                if (m0 + r < BATCH) v = tanhf(v);   // t == 0: h0 = tanh(xi)
                out[(size_t)(m0 + r) * LAT + n] = v;
            }
        }
    }
}

// ---------------------------------------------------------------------------
// Phase 2: one recurrence step, io[m][n] = tanh(io[m][n] + hprev @ Wh^T + bh).
// 256 blocks (1-D), WG tile 32x32, 4 waves split K (512 each), fragments
// streamed directly from global (16 rows x whole 128-B lines), split to
// hi/lo bf16 in-register; cross-wave K-reduce via LDS.
// v3: XCD-locality block swizzle — XCD x gets Wh strips bn_idx in [8x, 8x+8)
// for all 4 bm tiles: per-XCD working set = 2 MB Wh + 1 MB hprev < 4 MB L2.
// ---------------------------------------------------------------------------
__global__ __launch_bounds__(256, 2)
void k_step(const float* __restrict__ hprev, const float* __restrict__ Wh,
            const float* __restrict__ bias, float* __restrict__ io)
{
    __shared__ __align__(16) float part[4][32][32];   // [wave][row][col]

    const int tid  = threadIdx.x;
    const int lane = tid & 63;
    const int w    = tid >> 6;           // wave id == K-split index

    // XCD-aware decode (blocks round-robin across 8 XCDs by flat id).
    const int id     = blockIdx.x;
    const int xcd    = id & 7;
    const int j_     = id >> 3;          // 0..31 within XCD
    const int bn_idx = xcd * 8 + (j_ >> 2);
    const int bm_idx = j_ & 3;
    const int bn     = bn_idx * 32;      // output cols (rows of Wh)
    const int bm     = bm_idx * 32;      // batch rows

    const int fr = lane & 15;            // fragment row within 16
    const int kq = (lane >> 4) * 8;      // fragment K sub-offset (elements)

    const float* A0 = hprev + (size_t)(bm + fr)      * LAT;
    const float* A1 = hprev + (size_t)(bm + 16 + fr) * LAT;
    const float* B0 = Wh    + (size_t)(bn + fr)      * LAT;
    const float* B1 = Wh    + (size_t)(bn + 16 + fr) * LAT;

    f32x4 acc[2][2] = {};

    const int kbase = w * 512 + kq;
#pragma unroll
    for (int i = 0; i < 16; ++i) {
        const int k = kbase + i * 32;

        f32x4 a00 = *(const f32x4*)(A0 + k);
        f32x4 a01 = *(const f32x4*)(A0 + k + 4);
        f32x4 a10 = *(const f32x4*)(A1 + k);
        f32x4 a11 = *(const f32x4*)(A1 + k + 4);
        f32x4 b00 = *(const f32x4*)(B0 + k);
        f32x4 b01 = *(const f32x4*)(B0 + k + 4);
        f32x4 b10 = *(const f32x4*)(B1 + k);
        f32x4 b11 = *(const f32x4*)(B1 + k + 4);

        bf16x8 ah0, al0, ah1, al1, bh0, bl0, bh1, bl1;
        split8(a00, a01, ah0, al0);
        split8(a10, a11, ah1, al1);
        split8(b00, b01, bh0, bl0);
        split8(b10, b11, bh1, bl1);

        acc[0][0] = __builtin_amdgcn_mfma_f32_16x16x32_bf16(ah0, bh0, acc[0][0], 0, 0, 0);
        acc[0][1] = __builtin_amdgcn_mfma_f32_16x16x32_bf16(ah0, bh1, acc[0][1], 0, 0, 0);
        acc[1][0] = __builtin_amdgcn_mfma_f32_16x16x32_bf16(ah1, bh0, acc[1][0], 0, 0, 0);
        acc[1][1] = __builtin_amdgcn_mfma_f32_16x16x32_bf16(ah1, bh1, acc[1][1], 0, 0, 0);

        acc[0][0] = __builtin_amdgcn_mfma_f32_16x16x32_bf16(al0, bh0, acc[0][0], 0, 0, 0);
        acc[0][1] = __builtin_amdgcn_mfma_f32_16x16x32_bf16(al0, bh1, acc[0][1], 0, 0, 0);
        acc[1][0] = __builtin_amdgcn_mfma_f32_16x16x32_bf16(al1, bh0, acc[1][0], 0, 0, 0);
        acc[1][1] = __builtin_amdgcn_mfma_f32_16x16x32_bf16(al1, bh1, acc[1][1], 0, 0, 0);

        acc[0][0] = __builtin_amdgcn_mfma_f32_16x16x32_bf16(ah0, bl0, acc[0][0], 0, 0, 0);
        acc[0][1] = __builtin_amdgcn_mfma_f32_16x16x32_bf16(ah0, bl1, acc[0][1], 0, 0, 0);
        acc[1][0] = __builtin_amdgcn_mfma_f32_16x16x32_bf16(ah1, bl0, acc[1][0], 0, 0, 0);
        acc[1][1] = __builtin_amdgcn_mfma_f32_16x16x32_bf16(ah1, bl1, acc[1][1], 0, 0, 0);
    }

    // C-frag layout (m89): col = lane&15, row = (lane>>4)*4 + reg.
#pragma unroll
    for (int mi = 0; mi < 2; ++mi)
#pragma unroll
        for (int nj = 0; nj < 2; ++nj)
#pragma unroll
            for (int r = 0; r < 4; ++r)
                part[w][mi * 16 + (lane >> 4) * 4 + r][nj * 16 + fr] = acc[mi][nj][r];

    __syncthreads();

    const int row = tid >> 3;
    const int c   = (tid & 7) * 4;
    f32x4 s0 = *(const f32x4*)&part[0][row][c];
    f32x4 s1 = *(const f32x4*)&part[1][row][c];
    f32x4 s2 = *(const f32x4*)&part[2][row][c];
    f32x4 s3 = *(const f32x4*)&part[3][row][c];

    float* outp = io + (size_t)(bm + row) * LAT + bn + c;
    f32x4 xv = *(const f32x4*)outp;
    f32x4 bv = *(const f32x4*)(bias + bn + c);
    f32x4 o;
#pragma unroll
    for (int e = 0; e < 4; ++e)
        o[e] = tanhf(s0[e] + s1[e] + s2[e] + s3[e] + xv[e] + bv[e]);
    *(f32x4*)outp = o;
}

extern "C" void kernel_launch(void* const* d_in, const int* in_sizes, int n_in,
                              void* d_out, int out_size, void* d_ws, size_t ws_size,
                              hipStream_t stream) {
    const float* x  = (const float*)d_in[0];
    const float* Wi = (const float*)d_in[1];
    const float* bi = (const float*)d_in[2];
    const float* Wh = (const float*)d_in[3];
    const float* bh = (const float*)d_in[4];
    float* out = (float*)d_out;

    // Phase 1: xi (+bias) for all timesteps straight into d_out; tanh on t=0 rows.
    dim3 g1(LAT / 128, (T_STEPS * BATCH) / 128);   // (16, 256)
    k_xproj<<<g1, 256, 0, stream>>>(x, Wi, bi, out);

    // Phase 2: sequential recurrence, in-place on out[t].
    for (int t = 1; t < T_STEPS; ++t) {
        k_step<<<256, 256, 0, stream>>>(out + (size_t)(t - 1) * BATCH * LAT,
                                        Wh, bh,
                                        out + (size_t)t * BATCH * LAT);
    }
}